// Round 6
// baseline (1288.921 us; speedup 1.0000x reference)
//
#include <hip/hip_runtime.h>
#include <hip/hip_bf16.h>

// LightGCN on MI355X — pull CSR, radix-partitioned build, paired-edge gather.
//
// Round-5 evidence: lgcn_fill_kernel was the top dispatch (210us, WRITE_SIZE
// 249MB = 4M scattered 4B stores * 64B lines). Build is now two-level:
// bucket(128 nodes) partition with packed u32 pairs, then per-bucket LDS CSR
// (degrees, offsets, dis, row placement all block-local). Gather processes 2
// edges per wave (32 lanes x bf16x2), halving instruction issue per edge.

#ifndef EMB
#define EMB 64
#endif
#define BSHIFT 7                 // 128 nodes per bucket
#define BNODES (1 << BSHIFT)
#define NBMAX 1280               // LDS histogram capacity
#define CCAP 4800                // LDS pair-staging capacity per bucket

typedef unsigned int uint;
typedef unsigned short ushort;

static __device__ __forceinline__ float bf2f(ushort h) {
    union { unsigned u; float f; } v; v.u = (unsigned)h << 16; return v.f;
}
static __device__ __forceinline__ ushort f2bf(float f) {
    __hip_bfloat16 b = __float2bfloat16(f);
    return *(ushort*)&b;
}

// flag = 1 if edge_index is int64 (high words of first 128 entries all zero).
__global__ void lgcn_detect_kernel(const int* __restrict__ ei, int* __restrict__ flag) {
    __shared__ int any_nz;
    if (threadIdx.x == 0) any_nz = 0;
    __syncthreads();
    if (ei[2 * threadIdx.x + 1] != 0) atomicOr(&any_nz, 1);
    __syncthreads();
    if (threadIdx.x == 0) *flag = (any_nz == 0) ? 1 : 0;
}

static __device__ __forceinline__ int load_idx(const int* __restrict__ ei,
                                               long long elem, int is64,
                                               int n_nodes) {
    int v = is64 ? ei[elem << 1] : ei[elem];
    return min(max(v, 0), n_nodes - 1);
}

// ---- build step 1: bucket histogram (LDS-staged) ----
__global__ void lgcn_bhist_kernel(const int* __restrict__ ei,
                                  const int* __restrict__ flag,
                                  int* __restrict__ bcount,
                                  int n_edges, int n_nodes, int NB) {
    __shared__ int h[NBMAX];
    int t = threadIdx.x;
    int is64 = *flag;
    for (int i = t; i < NB; i += 256) h[i] = 0;
    __syncthreads();
    long long base = (long long)blockIdx.x * 4096 + t;
    #pragma unroll
    for (int k = 0; k < 16; ++k) {
        long long e = base + (long long)k * 256;
        if (e < n_edges) {
            int c = load_idx(ei, (long long)n_edges + e, is64, n_nodes);
            atomicAdd(&h[c >> BSHIFT], 1);
        }
    }
    __syncthreads();
    for (int i = t; i < NB; i += 256) {
        int v = h[i];
        if (v) atomicAdd(&bcount[i], v);
    }
}

// ---- build step 2: exclusive scan of bucket counts (single block) ----
// bucketBase[NB] = total; offsets[n_nodes] = total.
__global__ void lgcn_bscan_kernel(const int* __restrict__ bcount,
                                  int* __restrict__ bucketBase,
                                  int* __restrict__ offsets,
                                  int NB, int n_nodes) {
    __shared__ int tsum[256];
    int t = threadIdx.x;
    int K = (NB + 255) / 256;
    int base = t * K;
    int s = 0;
    for (int k = 0; k < K; ++k) {
        int i = base + k;
        if (i < NB) s += bcount[i];
    }
    tsum[t] = s;
    __syncthreads();
    for (int off = 1; off < 256; off <<= 1) {
        int x = (t >= off) ? tsum[t - off] : 0;
        __syncthreads();
        tsum[t] += x;
        __syncthreads();
    }
    int run = tsum[t] - s;   // exclusive prefix
    for (int k = 0; k < K; ++k) {
        int i = base + k;
        if (i < NB) { bucketBase[i] = run; run += bcount[i]; }
    }
    if (t == 255) {
        bucketBase[NB] = tsum[255];
        offsets[n_nodes] = tsum[255];
    }
}

// ---- build step 3: scatter packed (r<<7 | c&127) into bucket regions ----
__global__ void lgcn_bscatter_kernel(const int* __restrict__ ei,
                                     const int* __restrict__ flag,
                                     const int* __restrict__ bucketBase,
                                     int* __restrict__ bcur,
                                     uint* __restrict__ pairs,
                                     int n_edges, int n_nodes) {
    long long e = (long long)blockIdx.x * blockDim.x + threadIdx.x;
    if (e < n_edges) {
        int is64 = *flag;
        int r = load_idx(ei, e, is64, n_nodes);
        int c = load_idx(ei, (long long)n_edges + e, is64, n_nodes);
        int b = c >> BSHIFT;
        int pos = bucketBase[b] + atomicAdd(&bcur[b], 1);
        pairs[pos] = ((uint)r << BSHIFT) | (uint)(c & (BNODES - 1));
    }
}

// ---- build step 4: per-bucket CSR finalize (one block per bucket) ----
// Computes node degrees, offsets, dis, and places rows — all block-local.
__global__ void lgcn_bcsr_kernel(const uint* __restrict__ pairs,
                                 const int* __restrict__ bucketBase,
                                 int* __restrict__ offsets,
                                 int* __restrict__ csr_rows,
                                 float* __restrict__ dis,
                                 int n_nodes) {
    __shared__ int deg[BNODES];
    __shared__ int tmp[BNODES];
    __shared__ int loffx[BNODES];
    __shared__ int cur[BNODES];
    __shared__ uint lp[CCAP];
    int b = blockIdx.x;
    int t = threadIdx.x;            // 256 threads
    int nodeStart = b << BSHIFT;
    int base = bucketBase[b];
    int span = bucketBase[b + 1] - base;
    bool fits = (span <= CCAP);
    if (t < BNODES) deg[t] = 0;
    __syncthreads();
    for (int i = t; i < span; i += 256) {
        uint p = pairs[base + i];
        if (fits) lp[i] = p;
        atomicAdd(&deg[p & (BNODES - 1)], 1);
    }
    __syncthreads();
    if (t < BNODES) tmp[t] = deg[t];
    __syncthreads();
    for (int off = 1; off < BNODES; off <<= 1) {
        int x = (t < BNODES && t >= off) ? tmp[t - off] : 0;
        __syncthreads();
        if (t < BNODES) tmp[t] += x;
        __syncthreads();
    }
    if (t < BNODES) {
        int excl = tmp[t] - deg[t];
        loffx[t] = excl;
        cur[t] = 0;
        int node = nodeStart + t;
        if (node < n_nodes) {
            offsets[node] = base + excl;
            dis[node] = (deg[t] > 0) ? rsqrtf((float)deg[t]) : 0.0f;
        }
    }
    __syncthreads();
    for (int i = t; i < span; i += 256) {
        uint p = fits ? lp[i] : pairs[base + i];
        int cl = (int)(p & (BNODES - 1));
        int pos = loffx[cl] + atomicAdd(&cur[cl], 1);
        csr_rows[base + pos] = (int)(p >> BSHIFT);
    }
}

// ---- init: out(total,fp32) = x ; X(bf16) = x ----
__global__ void lgcn_init_kernel(const float* __restrict__ user_w,
                                 const float* __restrict__ item_w,
                                 float* __restrict__ total,
                                 ushort* __restrict__ xcatb,
                                 int n_user_elems, int n_total_elems) {
    int i = blockIdx.x * blockDim.x + threadIdx.x;
    if (i < n_total_elems) {
        float v = (i < n_user_elems) ? user_w[i] : item_w[i - n_user_elems];
        total[i] = v;
        xcatb[i] = f2bf(v);
    }
}

// ---- gather: one wave per node, 2 edges per iteration step ----
// lanes 0-31 handle edge j (dims 2*l2, 2*l2+1), lanes 32-63 handle edge j+1.
template <bool LAST>
__global__ void lgcn_gather_kernel(const int* __restrict__ csr_rows,
                                   const int* __restrict__ offsets,
                                   const float* __restrict__ dis,
                                   const ushort* __restrict__ xin,
                                   ushort* __restrict__ xout,
                                   float* __restrict__ total,
                                   int n_nodes) {
    long long tid = (long long)blockIdx.x * blockDim.x + threadIdx.x;
    int gid  = (int)(tid >> 6);
    int lane = threadIdx.x & 63;
    int half = lane >> 5;
    int l2   = lane & 31;
    int c = gid;
    if (c >= n_nodes) return;
    int beg = offsets[c];
    int end = offsets[c + 1];
    float dc = dis[c];
    float a0x = 0.f, a0y = 0.f, a1x = 0.f, a1y = 0.f;
    int j = beg;
    for (; j + 4 <= end; j += 4) {            // 4 edges: (j+half), (j+2+half)
        int r0 = csr_rows[j + half];
        int r1 = csr_rows[j + 2 + half];
        float w0 = dis[r0];
        float w1 = dis[r1];
        ushort2 b0 = *(const ushort2*)(xin + (size_t)r0 * EMB + 2 * l2);
        ushort2 b1 = *(const ushort2*)(xin + (size_t)r1 * EMB + 2 * l2);
        a0x += w0 * bf2f(b0.x);  a0y += w0 * bf2f(b0.y);
        a1x += w1 * bf2f(b1.x);  a1y += w1 * bf2f(b1.y);
    }
    for (; j < end; j += 2) {                 // tail: up to 2 edges per step
        int jj = j + half;
        int r = csr_rows[min(jj, end - 1)];
        float w = (jj < end) ? dis[r] : 0.0f;
        ushort2 b0 = *(const ushort2*)(xin + (size_t)r * EMB + 2 * l2);
        a0x += w * bf2f(b0.x);  a0y += w * bf2f(b0.y);
    }
    float ax = a0x + a1x, ay = a0y + a1y;
    ax += __shfl_xor(ax, 32, 64);
    ay += __shfl_xor(ay, 32, 64);
    ax *= dc; ay *= dc;
    if (half == 0) {
        size_t o2 = (size_t)c * (EMB / 2) + l2;
        float2* total2 = (float2*)total;
        if (!LAST) {
            ushort2 s; s.x = f2bf(ax); s.y = f2bf(ay);
            *(ushort2*)(xout + 2 * o2) = s;
            float2 tv = total2[o2];
            tv.x += ax; tv.y += ay;
            total2[o2] = tv;
        } else {
            float2 tv = total2[o2];
            tv.x = (tv.x + ax) * 0.25f;
            tv.y = (tv.y + ay) * 0.25f;
            total2[o2] = tv;
        }
    }
}

extern "C" void kernel_launch(void* const* d_in, const int* in_sizes, int n_in,
                              void* d_out, int out_size, void* d_ws, size_t ws_size,
                              hipStream_t stream) {
    // ---- role assignment by element count ----
    int ie = 0, iu = 1, ii = 2;
    {
        long long s[3] = { in_sizes[0], in_sizes[1], in_sizes[2] };
        ie = 0;
        if (s[1] > s[ie]) ie = 1;
        if (s[2] > s[ie]) ie = 2;
        int rest[2], k = 0;
        for (int j = 0; j < 3; ++j) if (j != ie) rest[k++] = j;
        if (s[rest[0]] >= s[rest[1]]) { iu = rest[0]; ii = rest[1]; }
        else                          { iu = rest[1]; ii = rest[0]; }
    }
    const int*   edge_index = (const int*)d_in[ie];
    const float* user_w     = (const float*)d_in[iu];
    const float* item_w     = (const float*)d_in[ii];
    float* out = (float*)d_out;   // fp32 `total`

    const int n_edges = in_sizes[ie] / 2;
    const int n_users = in_sizes[iu] / EMB;
    const int n_items = in_sizes[ii] / EMB;
    const int n_nodes = n_users + n_items;
    const int n_elems = n_nodes * EMB;
    const int NB = (n_nodes + BNODES - 1) / BNODES;   // 1172

    // ---- workspace carve (~57 MB; A aliases the dead `pairs` buffer) ----
    auto align_up = [](size_t x) { return (x + 1023) & ~(size_t)1023; };
    char* w = (char*)d_ws;
    int*   flag       = (int*)w; w += 1024;
    int*   bcount     = (int*)w; w += align_up((size_t)NB * sizeof(int));
    int*   bucketBase = (int*)w; w += align_up(((size_t)NB + 1) * sizeof(int));
    int*   bcur       = (int*)w; w += align_up((size_t)NB * sizeof(int));
    int*   offsets    = (int*)w; w += align_up(((size_t)n_nodes + 1) * sizeof(int));
    float* dis        = (float*)w; w += align_up((size_t)n_nodes * sizeof(float));
    int*   csr_rows   = (int*)w; w += align_up((size_t)n_edges * sizeof(int));
    // region U: pairs (n_edges u32 = 16MB) during build, then accA (bf16, 19.2MB)
    size_t u_bytes = align_up((size_t)n_elems * sizeof(ushort));
    size_t p_bytes = align_up((size_t)n_edges * sizeof(uint));
    uint*   pairs = (uint*)w;
    ushort* bufA  = (ushort*)w; w += (u_bytes > p_bytes ? u_bytes : p_bytes);
    ushort* bufX  = (ushort*)w;

    const int BLK = 256;
    const int gN = (n_elems + BLK - 1) / BLK;

    // 0) edge dtype detection
    lgcn_detect_kernel<<<1, 128, 0, stream>>>(edge_index, flag);

    // 1) bucket histogram -> scan -> pair scatter -> per-bucket CSR
    hipMemsetAsync(bcount, 0, (size_t)NB * sizeof(int), stream);
    hipMemsetAsync(bcur, 0, (size_t)NB * sizeof(int), stream);
    lgcn_bhist_kernel<<<(n_edges + 4095) / 4096, 256, 0, stream>>>(
        edge_index, flag, bcount, n_edges, n_nodes, NB);
    lgcn_bscan_kernel<<<1, 256, 0, stream>>>(bcount, bucketBase, offsets, NB, n_nodes);
    lgcn_bscatter_kernel<<<(n_edges + BLK - 1) / BLK, BLK, 0, stream>>>(
        edge_index, flag, bucketBase, bcur, pairs, n_edges, n_nodes);
    lgcn_bcsr_kernel<<<NB, 256, 0, stream>>>(
        pairs, bucketBase, offsets, csr_rows, dis, n_nodes);

    // 2) init: out = x (fp32), X = bf16(x)
    lgcn_init_kernel<<<gN, BLK, 0, stream>>>(user_w, item_w, out, bufX,
                                             n_users * EMB, n_elems);

    // 3) 3 pull layers (X -> A -> X -> out), one wave per node
    {
        long long n_thr = (long long)n_nodes * 64;
        int gW = (int)((n_thr + BLK - 1) / BLK);
        lgcn_gather_kernel<false><<<gW, BLK, 0, stream>>>(
            csr_rows, offsets, dis, bufX, bufA, out, n_nodes);
        lgcn_gather_kernel<false><<<gW, BLK, 0, stream>>>(
            csr_rows, offsets, dis, bufA, bufX, out, n_nodes);
        lgcn_gather_kernel<true><<<gW, BLK, 0, stream>>>(
            csr_rows, offsets, dis, bufX, nullptr, out, n_nodes);
    }
}

// Round 7
// 866.877 us; speedup vs baseline: 1.4869x; 1.4869x over previous
//
#include <hip/hip_runtime.h>
#include <hip/hip_bf16.h>

// LightGCN on MI355X — pull CSR (round-5 build) + paired-edge gather (round-6).
//
// Round-6 post-mortem: bucket scatter with 1172 cursors serialized on
// same-address atomics (~200ns L2 round trip x 3413 ops/address = 723us).
// Round-5 fill (150k cursors, 27 ops/address) is contention-free; its cost
// is 249MB of fragmented 64B-line writes at ~1.2TB/s = 210us. Keep that.
// Gather: one wave per destination, 2 edges/step (32 lanes x bf16x2).

#ifndef EMB
#define EMB 64
#endif
#define SCHUNK 2048   // elements per scan block (256 thr x 8)

typedef unsigned int uint;
typedef unsigned short ushort;

static __device__ __forceinline__ float bf2f(ushort h) {
    union { unsigned u; float f; } v; v.u = (unsigned)h << 16; return v.f;
}
static __device__ __forceinline__ ushort f2bf(float f) {
    __hip_bfloat16 b = __float2bfloat16(f);
    return *(ushort*)&b;
}

// flag = 1 if edge_index is int64 (high words of first 128 entries all zero).
__global__ void lgcn_detect_kernel(const int* __restrict__ ei, int* __restrict__ flag) {
    __shared__ int any_nz;
    if (threadIdx.x == 0) any_nz = 0;
    __syncthreads();
    if (ei[2 * threadIdx.x + 1] != 0) atomicOr(&any_nz, 1);
    __syncthreads();
    if (threadIdx.x == 0) *flag = (any_nz == 0) ? 1 : 0;
}

static __device__ __forceinline__ int load_idx(const int* __restrict__ ei,
                                               long long elem, int is64,
                                               int n_nodes) {
    int v = is64 ? ei[elem << 1] : ei[elem];
    return min(max(v, 0), n_nodes - 1);
}

// deg[col[e]] += 1  (int atomics on 150k counters — no contention)
__global__ void lgcn_hist_kernel(const int* __restrict__ ei,
                                 const int* __restrict__ flag,
                                 int* __restrict__ deg,
                                 int n_edges, int n_nodes) {
    int e = blockIdx.x * blockDim.x + threadIdx.x;
    if (e < n_edges) {
        int c = load_idx(ei, (long long)n_edges + e, *flag, n_nodes);
        atomicAdd(&deg[c], 1);
    }
}

__global__ void lgcn_dis_kernel(const int* __restrict__ deg,
                                float* __restrict__ dis, int n_nodes) {
    int i = blockIdx.x * blockDim.x + threadIdx.x;
    if (i < n_nodes) {
        int d = deg[i];
        dis[i] = (d > 0) ? rsqrtf((float)d) : 0.0f;
    }
}

// --- 3-phase exclusive scan of deg -> offsets ---
__global__ void lgcn_scanA_kernel(const int* __restrict__ deg,
                                  int* __restrict__ offsets,
                                  int* __restrict__ partials, int n) {
    __shared__ int tsum[256];
    const int t = threadIdx.x;
    const int base = blockIdx.x * SCHUNK + t * 8;
    int vals[8];
    int s = 0;
    #pragma unroll
    for (int k = 0; k < 8; ++k) {
        int idx = base + k;
        int v = (idx < n) ? deg[idx] : 0;
        vals[k] = s;
        s += v;
    }
    tsum[t] = s;
    __syncthreads();
    #pragma unroll
    for (int off = 1; off < 256; off <<= 1) {
        int x = (t >= off) ? tsum[t - off] : 0;
        __syncthreads();
        tsum[t] += x;
        __syncthreads();
    }
    int texcl = tsum[t] - s;
    #pragma unroll
    for (int k = 0; k < 8; ++k) {
        int idx = base + k;
        if (idx < n) offsets[idx] = texcl + vals[k];
    }
    if (t == 255) partials[blockIdx.x] = tsum[255];
}

__global__ void lgcn_scanB_kernel(int* __restrict__ partials,
                                  int* __restrict__ offsets, int nb, int n) {
    __shared__ int tsum[256];
    const int t = threadIdx.x;
    int v = (t < nb) ? partials[t] : 0;
    tsum[t] = v;
    __syncthreads();
    #pragma unroll
    for (int off = 1; off < 256; off <<= 1) {
        int x = (t >= off) ? tsum[t - off] : 0;
        __syncthreads();
        tsum[t] += x;
        __syncthreads();
    }
    if (t < nb) partials[t] = tsum[t] - v;
    if (t == 255) offsets[n] = tsum[255];
}

__global__ void lgcn_scanC_kernel(int* __restrict__ offsets,
                                  const int* __restrict__ partials, int n) {
    int i = blockIdx.x * blockDim.x + threadIdx.x;
    if (i < n) offsets[i] += partials[i / SCHUNK];
}

// fill: csr_rows[offsets[c] + cursor[c]++] = r   (150k cursors)
__global__ void lgcn_fill_kernel(const int* __restrict__ ei,
                                 const int* __restrict__ flag,
                                 const int* __restrict__ offsets,
                                 int* __restrict__ cursor,
                                 int* __restrict__ csr_rows,
                                 int n_edges, int n_nodes) {
    int e = blockIdx.x * blockDim.x + threadIdx.x;
    if (e < n_edges) {
        int is64 = *flag;
        int r = load_idx(ei, (long long)e, is64, n_nodes);
        int c = load_idx(ei, (long long)n_edges + e, is64, n_nodes);
        int pos = offsets[c] + atomicAdd(&cursor[c], 1);
        csr_rows[pos] = r;
    }
}

// init: out(total,fp32) = x ; X(bf16) = x
__global__ void lgcn_init_kernel(const float* __restrict__ user_w,
                                 const float* __restrict__ item_w,
                                 float* __restrict__ total,
                                 ushort* __restrict__ xcatb,
                                 int n_user_elems, int n_total_elems) {
    int i = blockIdx.x * blockDim.x + threadIdx.x;
    if (i < n_total_elems) {
        float v = (i < n_user_elems) ? user_w[i] : item_w[i - n_user_elems];
        total[i] = v;
        xcatb[i] = f2bf(v);
    }
}

// gather: one wave per node, 2 edges per step (lane halves), bf16x2 per lane.
template <bool LAST>
__global__ void lgcn_gather_kernel(const int* __restrict__ csr_rows,
                                   const int* __restrict__ offsets,
                                   const float* __restrict__ dis,
                                   const ushort* __restrict__ xin,
                                   ushort* __restrict__ xout,
                                   float* __restrict__ total,
                                   int n_nodes) {
    long long tid = (long long)blockIdx.x * blockDim.x + threadIdx.x;
    int gid  = (int)(tid >> 6);
    int lane = threadIdx.x & 63;
    int half = lane >> 5;
    int l2   = lane & 31;
    int c = gid;
    if (c >= n_nodes) return;
    int beg = offsets[c];
    int end = offsets[c + 1];
    float dc = dis[c];
    float a0x = 0.f, a0y = 0.f, a1x = 0.f, a1y = 0.f;
    int j = beg;
    for (; j + 4 <= end; j += 4) {
        int r0 = csr_rows[j + half];
        int r1 = csr_rows[j + 2 + half];
        float w0 = dis[r0];
        float w1 = dis[r1];
        ushort2 b0 = *(const ushort2*)(xin + (size_t)r0 * EMB + 2 * l2);
        ushort2 b1 = *(const ushort2*)(xin + (size_t)r1 * EMB + 2 * l2);
        a0x += w0 * bf2f(b0.x);  a0y += w0 * bf2f(b0.y);
        a1x += w1 * bf2f(b1.x);  a1y += w1 * bf2f(b1.y);
    }
    for (; j < end; j += 2) {
        int jj = j + half;
        int r = csr_rows[min(jj, end - 1)];
        float w = (jj < end) ? dis[r] : 0.0f;
        ushort2 b0 = *(const ushort2*)(xin + (size_t)r * EMB + 2 * l2);
        a0x += w * bf2f(b0.x);  a0y += w * bf2f(b0.y);
    }
    float ax = a0x + a1x, ay = a0y + a1y;
    ax += __shfl_xor(ax, 32, 64);
    ay += __shfl_xor(ay, 32, 64);
    ax *= dc; ay *= dc;
    if (half == 0) {
        size_t o2 = (size_t)c * (EMB / 2) + l2;
        float2* total2 = (float2*)total;
        if (!LAST) {
            ushort2 s; s.x = f2bf(ax); s.y = f2bf(ay);
            *(ushort2*)(xout + 2 * o2) = s;
            float2 tv = total2[o2];
            tv.x += ax; tv.y += ay;
            total2[o2] = tv;
        } else {
            float2 tv = total2[o2];
            tv.x = (tv.x + ax) * 0.25f;
            tv.y = (tv.y + ay) * 0.25f;
            total2[o2] = tv;
        }
    }
}

extern "C" void kernel_launch(void* const* d_in, const int* in_sizes, int n_in,
                              void* d_out, int out_size, void* d_ws, size_t ws_size,
                              hipStream_t stream) {
    // ---- role assignment by element count ----
    int ie = 0, iu = 1, ii = 2;
    {
        long long s[3] = { in_sizes[0], in_sizes[1], in_sizes[2] };
        ie = 0;
        if (s[1] > s[ie]) ie = 1;
        if (s[2] > s[ie]) ie = 2;
        int rest[2], k = 0;
        for (int j = 0; j < 3; ++j) if (j != ie) rest[k++] = j;
        if (s[rest[0]] >= s[rest[1]]) { iu = rest[0]; ii = rest[1]; }
        else                          { iu = rest[1]; ii = rest[0]; }
    }
    const int*   edge_index = (const int*)d_in[ie];
    const float* user_w     = (const float*)d_in[iu];
    const float* item_w     = (const float*)d_in[ii];
    float* out = (float*)d_out;   // fp32 `total`

    const int n_edges = in_sizes[ie] / 2;
    const int n_users = in_sizes[iu] / EMB;
    const int n_items = in_sizes[ii] / EMB;
    const int n_nodes = n_users + n_items;
    const int n_elems = n_nodes * EMB;

    // ---- workspace carve (~56 MB) ----
    auto align_up = [](size_t x) { return (x + 1023) & ~(size_t)1023; };
    char* w = (char*)d_ws;
    int*   flag     = (int*)w;   w += 1024;
    int*   deg      = (int*)w;   w += align_up((size_t)n_nodes * sizeof(int));
    float* dis      = (float*)w; w += align_up((size_t)n_nodes * sizeof(float));
    int*   offsets  = (int*)w;   w += align_up(((size_t)n_nodes + 1) * sizeof(int));
    int*   cursor   = (int*)w;   w += align_up((size_t)n_nodes * sizeof(int));
    int*   partials = (int*)w;   w += 4096;
    int*   csr_rows = (int*)w;   w += align_up((size_t)n_edges * sizeof(int));
    ushort* bufX    = (ushort*)w; w += align_up((size_t)n_elems * sizeof(ushort));
    ushort* bufA    = (ushort*)w;

    const int BLK = 256;
    const int gE = (n_edges + BLK - 1) / BLK;
    const int gN = (n_elems + BLK - 1) / BLK;
    const int gV = (n_nodes + BLK - 1) / BLK;
    const int nb = (n_nodes + SCHUNK - 1) / SCHUNK;

    // 0) edge dtype detection
    lgcn_detect_kernel<<<1, 128, 0, stream>>>(edge_index, flag);

    // 1) degree histogram + dis
    hipMemsetAsync(deg, 0, (size_t)n_nodes * sizeof(int), stream);
    lgcn_hist_kernel<<<gE, BLK, 0, stream>>>(edge_index, flag, deg, n_edges, n_nodes);
    lgcn_dis_kernel<<<gV, BLK, 0, stream>>>(deg, dis, n_nodes);

    // 2) exclusive scan deg -> offsets
    lgcn_scanA_kernel<<<nb, 256, 0, stream>>>(deg, offsets, partials, n_nodes);
    lgcn_scanB_kernel<<<1, 256, 0, stream>>>(partials, offsets, nb, n_nodes);
    lgcn_scanC_kernel<<<gV, BLK, 0, stream>>>(offsets, partials, n_nodes);

    // 3) CSR fill
    hipMemsetAsync(cursor, 0, (size_t)n_nodes * sizeof(int), stream);
    lgcn_fill_kernel<<<gE, BLK, 0, stream>>>(edge_index, flag, offsets, cursor,
                                             csr_rows, n_edges, n_nodes);

    // 4) init: out = x (fp32), X = bf16(x)
    lgcn_init_kernel<<<gN, BLK, 0, stream>>>(user_w, item_w, out, bufX,
                                             n_users * EMB, n_elems);

    // 5) 3 pull layers (X -> A -> X -> out), one wave per node
    {
        long long n_thr = (long long)n_nodes * 64;
        int gW = (int)((n_thr + BLK - 1) / BLK);
        lgcn_gather_kernel<false><<<gW, BLK, 0, stream>>>(
            csr_rows, offsets, dis, bufX, bufA, out, n_nodes);
        lgcn_gather_kernel<false><<<gW, BLK, 0, stream>>>(
            csr_rows, offsets, dis, bufA, bufX, out, n_nodes);
        lgcn_gather_kernel<true><<<gW, BLK, 0, stream>>>(
            csr_rows, offsets, dis, bufX, nullptr, out, n_nodes);
    }
}

// Round 8
// 765.132 us; speedup vs baseline: 1.6846x; 1.1330x over previous
//
#include <hip/hip_runtime.h>
#include <hip/hip_bf16.h>

// LightGCN on MI355X — pull CSR (round-5 build) + deep-unrolled gather.
//
// Round-7 analysis: 3 gather layers ~190us each are concurrency-limited
// (512B in flight/wave x 2000 waves ~= 1MB = BW*latency at 2.7TB/s). This
// version puts 2KB/wave in flight: 8 lanes per edge (uint4=16B each, one
// wave-instruction = 8 edges = 1KB), unrolled x2. Reduction: shfl_xor
// 8/16/32; lanes 0-7 write uint4 bf16 + float4 totals.
// Build (hist/scan/fill, 150k cursors) unchanged from round 7.

#ifndef EMB
#define EMB 64
#endif
#define SCHUNK 2048   // elements per scan block (256 thr x 8)

typedef unsigned int uint;
typedef unsigned short ushort;

static __device__ __forceinline__ ushort f2bf(float f) {
    __hip_bfloat16 b = __float2bfloat16(f);
    return *(ushort*)&b;
}

// u = two packed bf16; accumulate w * {lo,hi} into aL,aH.
static __device__ __forceinline__ void acc2(uint u, float w, float& aL, float& aH) {
    union { uint x; float f; } lo, hi;
    lo.x = u << 16;
    hi.x = u & 0xffff0000u;
    aL = fmaf(w, lo.f, aL);
    aH = fmaf(w, hi.f, aH);
}

// flag = 1 if edge_index is int64 (high words of first 128 entries all zero).
__global__ void lgcn_detect_kernel(const int* __restrict__ ei, int* __restrict__ flag) {
    __shared__ int any_nz;
    if (threadIdx.x == 0) any_nz = 0;
    __syncthreads();
    if (ei[2 * threadIdx.x + 1] != 0) atomicOr(&any_nz, 1);
    __syncthreads();
    if (threadIdx.x == 0) *flag = (any_nz == 0) ? 1 : 0;
}

static __device__ __forceinline__ int load_idx(const int* __restrict__ ei,
                                               long long elem, int is64,
                                               int n_nodes) {
    int v = is64 ? ei[elem << 1] : ei[elem];
    return min(max(v, 0), n_nodes - 1);
}

// deg[col[e]] += 1  (int atomics on 150k counters — no contention)
__global__ void lgcn_hist_kernel(const int* __restrict__ ei,
                                 const int* __restrict__ flag,
                                 int* __restrict__ deg,
                                 int n_edges, int n_nodes) {
    int e = blockIdx.x * blockDim.x + threadIdx.x;
    if (e < n_edges) {
        int c = load_idx(ei, (long long)n_edges + e, *flag, n_nodes);
        atomicAdd(&deg[c], 1);
    }
}

__global__ void lgcn_dis_kernel(const int* __restrict__ deg,
                                float* __restrict__ dis, int n_nodes) {
    int i = blockIdx.x * blockDim.x + threadIdx.x;
    if (i < n_nodes) {
        int d = deg[i];
        dis[i] = (d > 0) ? rsqrtf((float)d) : 0.0f;
    }
}

// --- 3-phase exclusive scan of deg -> offsets ---
__global__ void lgcn_scanA_kernel(const int* __restrict__ deg,
                                  int* __restrict__ offsets,
                                  int* __restrict__ partials, int n) {
    __shared__ int tsum[256];
    const int t = threadIdx.x;
    const int base = blockIdx.x * SCHUNK + t * 8;
    int vals[8];
    int s = 0;
    #pragma unroll
    for (int k = 0; k < 8; ++k) {
        int idx = base + k;
        int v = (idx < n) ? deg[idx] : 0;
        vals[k] = s;
        s += v;
    }
    tsum[t] = s;
    __syncthreads();
    #pragma unroll
    for (int off = 1; off < 256; off <<= 1) {
        int x = (t >= off) ? tsum[t - off] : 0;
        __syncthreads();
        tsum[t] += x;
        __syncthreads();
    }
    int texcl = tsum[t] - s;
    #pragma unroll
    for (int k = 0; k < 8; ++k) {
        int idx = base + k;
        if (idx < n) offsets[idx] = texcl + vals[k];
    }
    if (t == 255) partials[blockIdx.x] = tsum[255];
}

__global__ void lgcn_scanB_kernel(int* __restrict__ partials,
                                  int* __restrict__ offsets, int nb, int n) {
    __shared__ int tsum[256];
    const int t = threadIdx.x;
    int v = (t < nb) ? partials[t] : 0;
    tsum[t] = v;
    __syncthreads();
    #pragma unroll
    for (int off = 1; off < 256; off <<= 1) {
        int x = (t >= off) ? tsum[t - off] : 0;
        __syncthreads();
        tsum[t] += x;
        __syncthreads();
    }
    if (t < nb) partials[t] = tsum[t] - v;
    if (t == 255) offsets[n] = tsum[255];
}

__global__ void lgcn_scanC_kernel(int* __restrict__ offsets,
                                  const int* __restrict__ partials, int n) {
    int i = blockIdx.x * blockDim.x + threadIdx.x;
    if (i < n) offsets[i] += partials[i / SCHUNK];
}

// fill: csr_rows[offsets[c] + cursor[c]++] = r   (150k cursors)
__global__ void lgcn_fill_kernel(const int* __restrict__ ei,
                                 const int* __restrict__ flag,
                                 const int* __restrict__ offsets,
                                 int* __restrict__ cursor,
                                 int* __restrict__ csr_rows,
                                 int n_edges, int n_nodes) {
    int e = blockIdx.x * blockDim.x + threadIdx.x;
    if (e < n_edges) {
        int is64 = *flag;
        int r = load_idx(ei, (long long)e, is64, n_nodes);
        int c = load_idx(ei, (long long)n_edges + e, is64, n_nodes);
        int pos = offsets[c] + atomicAdd(&cursor[c], 1);
        csr_rows[pos] = r;
    }
}

// init: out(total,fp32) = x ; X(bf16) = x
__global__ void lgcn_init_kernel(const float* __restrict__ user_w,
                                 const float* __restrict__ item_w,
                                 float* __restrict__ total,
                                 ushort* __restrict__ xcatb,
                                 int n_user_elems, int n_total_elems) {
    int i = blockIdx.x * blockDim.x + threadIdx.x;
    if (i < n_total_elems) {
        float v = (i < n_user_elems) ? user_w[i] : item_w[i - n_user_elems];
        total[i] = v;
        xcatb[i] = f2bf(v);
    }
}

// gather v3: one wave per node; 8 lanes per edge (uint4 = 16B per lane);
// one wave-wide load = 8 edges = 1KB; unrolled x2 = 2KB in flight per wave.
template <bool LAST>
__global__ void lgcn_gather_kernel(const int* __restrict__ csr_rows,
                                   const int* __restrict__ offsets,
                                   const float* __restrict__ dis,
                                   const ushort* __restrict__ xin,
                                   ushort* __restrict__ xout,
                                   float* __restrict__ total,
                                   int n_nodes) {
    long long tid = (long long)blockIdx.x * blockDim.x + threadIdx.x;
    int c    = (int)(tid >> 6);
    int lane = threadIdx.x & 63;
    int oct  = lane >> 3;   // edge slot 0..7 within a group
    int o8   = lane & 7;    // which 16B chunk of the 128B row
    if (c >= n_nodes) return;
    int beg = offsets[c];
    int end = offsets[c + 1];
    float dc = dis[c];
    float a[8];
    #pragma unroll
    for (int k = 0; k < 8; ++k) a[k] = 0.0f;

    for (int j = beg; j < end; j += 16) {
        int j0 = j + oct;
        int j1 = j + 8 + oct;
        bool v0 = j0 < end;
        bool v1 = j1 < end;
        int r0 = csr_rows[v0 ? j0 : beg];
        int r1 = csr_rows[v1 ? j1 : beg];
        float w0 = v0 ? dis[r0] : 0.0f;
        float w1 = v1 ? dis[r1] : 0.0f;
        uint4 q0 = *(const uint4*)(xin + (size_t)r0 * EMB + o8 * 8);
        uint4 q1 = *(const uint4*)(xin + (size_t)r1 * EMB + o8 * 8);
        acc2(q0.x, w0, a[0], a[1]);
        acc2(q0.y, w0, a[2], a[3]);
        acc2(q0.z, w0, a[4], a[5]);
        acc2(q0.w, w0, a[6], a[7]);
        acc2(q1.x, w1, a[0], a[1]);
        acc2(q1.y, w1, a[2], a[3]);
        acc2(q1.z, w1, a[4], a[5]);
        acc2(q1.w, w1, a[6], a[7]);
    }

    // reduce across the 8 edge slots (lane bits 3,4,5)
    #pragma unroll
    for (int k = 0; k < 8; ++k) {
        a[k] += __shfl_xor(a[k], 8, 64);
        a[k] += __shfl_xor(a[k], 16, 64);
        a[k] += __shfl_xor(a[k], 32, 64);
    }

    if (oct == 0) {   // lanes 0..7; lane l holds dims [8*l, 8*l+8)
        #pragma unroll
        for (int k = 0; k < 8; ++k) a[k] *= dc;
        size_t fo = (size_t)c * EMB + o8 * 8;
        float4* t0 = (float4*)(total + fo);
        if (!LAST) {
            uint4 s;
            s.x = ((uint)f2bf(a[1]) << 16) | f2bf(a[0]);
            s.y = ((uint)f2bf(a[3]) << 16) | f2bf(a[2]);
            s.z = ((uint)f2bf(a[5]) << 16) | f2bf(a[4]);
            s.w = ((uint)f2bf(a[7]) << 16) | f2bf(a[6]);
            *(uint4*)(xout + fo) = s;
            float4 t = t0[0];
            t.x += a[0]; t.y += a[1]; t.z += a[2]; t.w += a[3];
            t0[0] = t;
            float4 u = t0[1];
            u.x += a[4]; u.y += a[5]; u.z += a[6]; u.w += a[7];
            t0[1] = u;
        } else {
            float4 t = t0[0];
            t.x = (t.x + a[0]) * 0.25f; t.y = (t.y + a[1]) * 0.25f;
            t.z = (t.z + a[2]) * 0.25f; t.w = (t.w + a[3]) * 0.25f;
            t0[0] = t;
            float4 u = t0[1];
            u.x = (u.x + a[4]) * 0.25f; u.y = (u.y + a[5]) * 0.25f;
            u.z = (u.z + a[6]) * 0.25f; u.w = (u.w + a[7]) * 0.25f;
            t0[1] = u;
        }
    }
}

extern "C" void kernel_launch(void* const* d_in, const int* in_sizes, int n_in,
                              void* d_out, int out_size, void* d_ws, size_t ws_size,
                              hipStream_t stream) {
    // ---- role assignment by element count ----
    int ie = 0, iu = 1, ii = 2;
    {
        long long s[3] = { in_sizes[0], in_sizes[1], in_sizes[2] };
        ie = 0;
        if (s[1] > s[ie]) ie = 1;
        if (s[2] > s[ie]) ie = 2;
        int rest[2], k = 0;
        for (int j = 0; j < 3; ++j) if (j != ie) rest[k++] = j;
        if (s[rest[0]] >= s[rest[1]]) { iu = rest[0]; ii = rest[1]; }
        else                          { iu = rest[1]; ii = rest[0]; }
    }
    const int*   edge_index = (const int*)d_in[ie];
    const float* user_w     = (const float*)d_in[iu];
    const float* item_w     = (const float*)d_in[ii];
    float* out = (float*)d_out;   // fp32 `total`

    const int n_edges = in_sizes[ie] / 2;
    const int n_users = in_sizes[iu] / EMB;
    const int n_items = in_sizes[ii] / EMB;
    const int n_nodes = n_users + n_items;
    const int n_elems = n_nodes * EMB;

    // ---- workspace carve (~56 MB) ----
    auto align_up = [](size_t x) { return (x + 1023) & ~(size_t)1023; };
    char* w = (char*)d_ws;
    int*   flag     = (int*)w;   w += 1024;
    int*   deg      = (int*)w;   w += align_up((size_t)n_nodes * sizeof(int));
    float* dis      = (float*)w; w += align_up((size_t)n_nodes * sizeof(float));
    int*   offsets  = (int*)w;   w += align_up(((size_t)n_nodes + 1) * sizeof(int));
    int*   cursor   = (int*)w;   w += align_up((size_t)n_nodes * sizeof(int));
    int*   partials = (int*)w;   w += 4096;
    int*   csr_rows = (int*)w;   w += align_up((size_t)n_edges * sizeof(int));
    ushort* bufX    = (ushort*)w; w += align_up((size_t)n_elems * sizeof(ushort));
    ushort* bufA    = (ushort*)w;

    const int BLK = 256;
    const int gE = (n_edges + BLK - 1) / BLK;
    const int gN = (n_elems + BLK - 1) / BLK;
    const int gV = (n_nodes + BLK - 1) / BLK;
    const int nb = (n_nodes + SCHUNK - 1) / SCHUNK;

    // 0) edge dtype detection
    lgcn_detect_kernel<<<1, 128, 0, stream>>>(edge_index, flag);

    // 1) degree histogram + dis
    hipMemsetAsync(deg, 0, (size_t)n_nodes * sizeof(int), stream);
    lgcn_hist_kernel<<<gE, BLK, 0, stream>>>(edge_index, flag, deg, n_edges, n_nodes);
    lgcn_dis_kernel<<<gV, BLK, 0, stream>>>(deg, dis, n_nodes);

    // 2) exclusive scan deg -> offsets
    lgcn_scanA_kernel<<<nb, 256, 0, stream>>>(deg, offsets, partials, n_nodes);
    lgcn_scanB_kernel<<<1, 256, 0, stream>>>(partials, offsets, nb, n_nodes);
    lgcn_scanC_kernel<<<gV, BLK, 0, stream>>>(offsets, partials, n_nodes);

    // 3) CSR fill
    hipMemsetAsync(cursor, 0, (size_t)n_nodes * sizeof(int), stream);
    lgcn_fill_kernel<<<gE, BLK, 0, stream>>>(edge_index, flag, offsets, cursor,
                                             csr_rows, n_edges, n_nodes);

    // 4) init: out = x (fp32), X = bf16(x)
    lgcn_init_kernel<<<gN, BLK, 0, stream>>>(user_w, item_w, out, bufX,
                                             n_users * EMB, n_elems);

    // 5) 3 pull layers (X -> A -> X -> out), one wave per node
    {
        long long n_thr = (long long)n_nodes * 64;
        int gW = (int)((n_thr + BLK - 1) / BLK);
        lgcn_gather_kernel<false><<<gW, BLK, 0, stream>>>(
            csr_rows, offsets, dis, bufX, bufA, out, n_nodes);
        lgcn_gather_kernel<false><<<gW, BLK, 0, stream>>>(
            csr_rows, offsets, dis, bufA, bufX, out, n_nodes);
        lgcn_gather_kernel<true><<<gW, BLK, 0, stream>>>(
            csr_rows, offsets, dis, bufX, nullptr, out, n_nodes);
    }
}

// Round 9
// 566.033 us; speedup vs baseline: 2.2771x; 1.3517x over previous
//
#include <hip/hip_runtime.h>
#include <hip/hip_bf16.h>

// LightGCN on MI355X — block-aggregated bucket build + deep-unrolled gather.
//
// Build history: fill with 150k cursors = no contention but 249MB fragmented
// line writebacks (245us); per-edge bucket atomics on 1172 cursors = 3413
// serialized ops/address (723us). This build aggregates per block: LDS
// histogram over 1172 buckets, ONE global atomic per (block,bucket) to
// reserve a run (123 blocks -> 25us max chain), contiguous run writes that
// merge in L2. Then per-bucket LDS CSR finalize (round-6 bcsr, proven).
// Gather: one wave/node, 8 lanes/edge uint4, 2KB in flight (round-8, proven).

#ifndef EMB
#define EMB 64
#endif
#define BSHIFT 7                 // 128 nodes per bucket
#define BNODES (1 << BSHIFT)
#define NBMAX 1280               // LDS histogram capacity
#define CCAP 4800                // LDS pair-staging capacity per bucket
#define CH 32768                 // edges per bscatter block

typedef unsigned int uint;
typedef unsigned short ushort;

static __device__ __forceinline__ ushort f2bf(float f) {
    __hip_bfloat16 b = __float2bfloat16(f);
    return *(ushort*)&b;
}

// u = two packed bf16; accumulate w * {lo,hi} into aL,aH.
static __device__ __forceinline__ void acc2(uint u, float w, float& aL, float& aH) {
    union { uint x; float f; } lo, hi;
    lo.x = u << 16;
    hi.x = u & 0xffff0000u;
    aL = fmaf(w, lo.f, aL);
    aH = fmaf(w, hi.f, aH);
}

// flag = 1 if edge_index is int64 (high words of first 128 entries all zero).
__global__ void lgcn_detect_kernel(const int* __restrict__ ei, int* __restrict__ flag) {
    __shared__ int any_nz;
    if (threadIdx.x == 0) any_nz = 0;
    __syncthreads();
    if (ei[2 * threadIdx.x + 1] != 0) atomicOr(&any_nz, 1);
    __syncthreads();
    if (threadIdx.x == 0) *flag = (any_nz == 0) ? 1 : 0;
}

static __device__ __forceinline__ int load_idx(const int* __restrict__ ei,
                                               long long elem, int is64,
                                               int n_nodes) {
    int v = is64 ? ei[elem << 1] : ei[elem];
    return min(max(v, 0), n_nodes - 1);
}

// ---- build step 1: bucket histogram (LDS-staged) ----
__global__ void lgcn_bhist_kernel(const int* __restrict__ ei,
                                  const int* __restrict__ flag,
                                  int* __restrict__ bcount,
                                  int n_edges, int n_nodes, int NB) {
    __shared__ int h[NBMAX];
    int t = threadIdx.x;
    int is64 = *flag;
    for (int i = t; i < NB; i += 256) h[i] = 0;
    __syncthreads();
    long long base = (long long)blockIdx.x * 4096 + t;
    #pragma unroll
    for (int k = 0; k < 16; ++k) {
        long long e = base + (long long)k * 256;
        if (e < n_edges) {
            int c = load_idx(ei, (long long)n_edges + e, is64, n_nodes);
            atomicAdd(&h[c >> BSHIFT], 1);
        }
    }
    __syncthreads();
    for (int i = t; i < NB; i += 256) {
        int v = h[i];
        if (v) atomicAdd(&bcount[i], v);
    }
}

// ---- build step 2: exclusive scan of bucket counts (single block) ----
__global__ void lgcn_bscan_kernel(const int* __restrict__ bcount,
                                  int* __restrict__ bucketBase,
                                  int* __restrict__ offsets,
                                  int NB, int n_nodes) {
    __shared__ int tsum[256];
    int t = threadIdx.x;
    int K = (NB + 255) / 256;
    int base = t * K;
    int s = 0;
    for (int k = 0; k < K; ++k) {
        int i = base + k;
        if (i < NB) s += bcount[i];
    }
    tsum[t] = s;
    __syncthreads();
    for (int off = 1; off < 256; off <<= 1) {
        int x = (t >= off) ? tsum[t - off] : 0;
        __syncthreads();
        tsum[t] += x;
        __syncthreads();
    }
    int run = tsum[t] - s;
    for (int k = 0; k < K; ++k) {
        int i = base + k;
        if (i < NB) { bucketBase[i] = run; run += bcount[i]; }
    }
    if (t == 255) {
        bucketBase[NB] = tsum[255];
        offsets[n_nodes] = tsum[255];
    }
}

// ---- build step 3: block-aggregated pair scatter ----
// Per block: LDS bucket histogram of its CH edges, one global atomic per
// (block,bucket) to reserve a contiguous run, then write packed pairs.
__global__ void lgcn_bscatter2_kernel(const int* __restrict__ ei,
                                      const int* __restrict__ flag,
                                      const int* __restrict__ bucketBase,
                                      int* __restrict__ bcur,
                                      uint* __restrict__ pairs,
                                      int n_edges, int n_nodes, int NB) {
    __shared__ int lcount[NBMAX];
    __shared__ int lbase[NBMAX];
    int t = threadIdx.x;
    int is64 = *flag;
    long long base = (long long)blockIdx.x * CH;
    for (int i = t; i < NB; i += 256) lcount[i] = 0;
    __syncthreads();
    // pass 1: local histogram
    for (int k = t; k < CH; k += 256) {
        long long e = base + k;
        if (e < n_edges) {
            int c = load_idx(ei, (long long)n_edges + e, is64, n_nodes);
            atomicAdd(&lcount[c >> BSHIFT], 1);
        }
    }
    __syncthreads();
    // reservation: one global atomic per non-empty bucket
    for (int i = t; i < NB; i += 256) {
        int cnt = lcount[i];
        lbase[i] = cnt ? (bucketBase[i] + atomicAdd(&bcur[i], cnt)) : 0;
        lcount[i] = 0;   // reuse as local cursor
    }
    __syncthreads();
    // pass 2: write pairs into reserved runs (contiguous per bucket-run)
    for (int k = t; k < CH; k += 256) {
        long long e = base + k;
        if (e < n_edges) {
            int r = load_idx(ei, e, is64, n_nodes);
            int c = load_idx(ei, (long long)n_edges + e, is64, n_nodes);
            int b = c >> BSHIFT;
            int pos = lbase[b] + atomicAdd(&lcount[b], 1);
            pairs[pos] = ((uint)r << BSHIFT) | (uint)(c & (BNODES - 1));
        }
    }
}

// ---- build step 4: per-bucket CSR finalize (one block per bucket) ----
__global__ void lgcn_bcsr_kernel(const uint* __restrict__ pairs,
                                 const int* __restrict__ bucketBase,
                                 int* __restrict__ offsets,
                                 int* __restrict__ csr_rows,
                                 float* __restrict__ dis,
                                 int n_nodes) {
    __shared__ int deg[BNODES];
    __shared__ int tmp[BNODES];
    __shared__ int loffx[BNODES];
    __shared__ int cur[BNODES];
    __shared__ uint lp[CCAP];
    int b = blockIdx.x;
    int t = threadIdx.x;            // 256 threads
    int nodeStart = b << BSHIFT;
    int base = bucketBase[b];
    int span = bucketBase[b + 1] - base;
    bool fits = (span <= CCAP);
    if (t < BNODES) deg[t] = 0;
    __syncthreads();
    for (int i = t; i < span; i += 256) {
        uint p = pairs[base + i];
        if (fits) lp[i] = p;
        atomicAdd(&deg[p & (BNODES - 1)], 1);
    }
    __syncthreads();
    if (t < BNODES) tmp[t] = deg[t];
    __syncthreads();
    for (int off = 1; off < BNODES; off <<= 1) {
        int x = (t < BNODES && t >= off) ? tmp[t - off] : 0;
        __syncthreads();
        if (t < BNODES) tmp[t] += x;
        __syncthreads();
    }
    if (t < BNODES) {
        int excl = tmp[t] - deg[t];
        loffx[t] = excl;
        cur[t] = 0;
        int node = nodeStart + t;
        if (node < n_nodes) {
            offsets[node] = base + excl;
            dis[node] = (deg[t] > 0) ? rsqrtf((float)deg[t]) : 0.0f;
        }
    }
    __syncthreads();
    for (int i = t; i < span; i += 256) {
        uint p = fits ? lp[i] : pairs[base + i];
        int cl = (int)(p & (BNODES - 1));
        int pos = loffx[cl] + atomicAdd(&cur[cl], 1);
        csr_rows[base + pos] = (int)(p >> BSHIFT);
    }
}

// init: out(total,fp32) = x ; X(bf16) = x
__global__ void lgcn_init_kernel(const float* __restrict__ user_w,
                                 const float* __restrict__ item_w,
                                 float* __restrict__ total,
                                 ushort* __restrict__ xcatb,
                                 int n_user_elems, int n_total_elems) {
    int i = blockIdx.x * blockDim.x + threadIdx.x;
    if (i < n_total_elems) {
        float v = (i < n_user_elems) ? user_w[i] : item_w[i - n_user_elems];
        total[i] = v;
        xcatb[i] = f2bf(v);
    }
}

// gather: one wave per node; 8 lanes per edge (uint4 = 16B per lane);
// one wave-wide load = 8 edges = 1KB; unrolled x2 = 2KB in flight per wave.
template <bool LAST>
__global__ void lgcn_gather_kernel(const int* __restrict__ csr_rows,
                                   const int* __restrict__ offsets,
                                   const float* __restrict__ dis,
                                   const ushort* __restrict__ xin,
                                   ushort* __restrict__ xout,
                                   float* __restrict__ total,
                                   int n_nodes) {
    long long tid = (long long)blockIdx.x * blockDim.x + threadIdx.x;
    int c    = (int)(tid >> 6);
    int lane = threadIdx.x & 63;
    int oct  = lane >> 3;   // edge slot 0..7 within a group
    int o8   = lane & 7;    // which 16B chunk of the 128B row
    if (c >= n_nodes) return;
    int beg = offsets[c];
    int end = offsets[c + 1];
    float dc = dis[c];
    float a[8];
    #pragma unroll
    for (int k = 0; k < 8; ++k) a[k] = 0.0f;

    for (int j = beg; j < end; j += 16) {
        int j0 = j + oct;
        int j1 = j + 8 + oct;
        bool v0 = j0 < end;
        bool v1 = j1 < end;
        int r0 = csr_rows[v0 ? j0 : beg];
        int r1 = csr_rows[v1 ? j1 : beg];
        float w0 = v0 ? dis[r0] : 0.0f;
        float w1 = v1 ? dis[r1] : 0.0f;
        uint4 q0 = *(const uint4*)(xin + (size_t)r0 * EMB + o8 * 8);
        uint4 q1 = *(const uint4*)(xin + (size_t)r1 * EMB + o8 * 8);
        acc2(q0.x, w0, a[0], a[1]);
        acc2(q0.y, w0, a[2], a[3]);
        acc2(q0.z, w0, a[4], a[5]);
        acc2(q0.w, w0, a[6], a[7]);
        acc2(q1.x, w1, a[0], a[1]);
        acc2(q1.y, w1, a[2], a[3]);
        acc2(q1.z, w1, a[4], a[5]);
        acc2(q1.w, w1, a[6], a[7]);
    }

    #pragma unroll
    for (int k = 0; k < 8; ++k) {
        a[k] += __shfl_xor(a[k], 8, 64);
        a[k] += __shfl_xor(a[k], 16, 64);
        a[k] += __shfl_xor(a[k], 32, 64);
    }

    if (oct == 0) {   // lanes 0..7; lane l holds dims [8*l, 8*l+8)
        #pragma unroll
        for (int k = 0; k < 8; ++k) a[k] *= dc;
        size_t fo = (size_t)c * EMB + o8 * 8;
        float4* t0 = (float4*)(total + fo);
        if (!LAST) {
            uint4 s;
            s.x = ((uint)f2bf(a[1]) << 16) | f2bf(a[0]);
            s.y = ((uint)f2bf(a[3]) << 16) | f2bf(a[2]);
            s.z = ((uint)f2bf(a[5]) << 16) | f2bf(a[4]);
            s.w = ((uint)f2bf(a[7]) << 16) | f2bf(a[6]);
            *(uint4*)(xout + fo) = s;
            float4 t = t0[0];
            t.x += a[0]; t.y += a[1]; t.z += a[2]; t.w += a[3];
            t0[0] = t;
            float4 u = t0[1];
            u.x += a[4]; u.y += a[5]; u.z += a[6]; u.w += a[7];
            t0[1] = u;
        } else {
            float4 t = t0[0];
            t.x = (t.x + a[0]) * 0.25f; t.y = (t.y + a[1]) * 0.25f;
            t.z = (t.z + a[2]) * 0.25f; t.w = (t.w + a[3]) * 0.25f;
            t0[0] = t;
            float4 u = t0[1];
            u.x = (u.x + a[4]) * 0.25f; u.y = (u.y + a[5]) * 0.25f;
            u.z = (u.z + a[6]) * 0.25f; u.w = (u.w + a[7]) * 0.25f;
            t0[1] = u;
        }
    }
}

extern "C" void kernel_launch(void* const* d_in, const int* in_sizes, int n_in,
                              void* d_out, int out_size, void* d_ws, size_t ws_size,
                              hipStream_t stream) {
    // ---- role assignment by element count ----
    int ie = 0, iu = 1, ii = 2;
    {
        long long s[3] = { in_sizes[0], in_sizes[1], in_sizes[2] };
        ie = 0;
        if (s[1] > s[ie]) ie = 1;
        if (s[2] > s[ie]) ie = 2;
        int rest[2], k = 0;
        for (int j = 0; j < 3; ++j) if (j != ie) rest[k++] = j;
        if (s[rest[0]] >= s[rest[1]]) { iu = rest[0]; ii = rest[1]; }
        else                          { iu = rest[1]; ii = rest[0]; }
    }
    const int*   edge_index = (const int*)d_in[ie];
    const float* user_w     = (const float*)d_in[iu];
    const float* item_w     = (const float*)d_in[ii];
    float* out = (float*)d_out;   // fp32 `total`

    const int n_edges = in_sizes[ie] / 2;
    const int n_users = in_sizes[iu] / EMB;
    const int n_items = in_sizes[ii] / EMB;
    const int n_nodes = n_users + n_items;
    const int n_elems = n_nodes * EMB;
    const int NB = (n_nodes + BNODES - 1) / BNODES;   // 1172

    // ---- workspace carve (~56 MB; bufA aliases dead `pairs`) ----
    auto align_up = [](size_t x) { return (x + 1023) & ~(size_t)1023; };
    char* w = (char*)d_ws;
    int*   flag       = (int*)w; w += 1024;
    int*   bcount     = (int*)w; w += align_up((size_t)NB * sizeof(int));
    int*   bucketBase = (int*)w; w += align_up(((size_t)NB + 1) * sizeof(int));
    int*   bcur       = (int*)w; w += align_up((size_t)NB * sizeof(int));
    int*   offsets    = (int*)w; w += align_up(((size_t)n_nodes + 1) * sizeof(int));
    float* dis        = (float*)w; w += align_up((size_t)n_nodes * sizeof(float));
    int*   csr_rows   = (int*)w; w += align_up((size_t)n_edges * sizeof(int));
    size_t u_bytes = align_up((size_t)n_elems * sizeof(ushort));
    size_t p_bytes = align_up((size_t)n_edges * sizeof(uint));
    uint*   pairs = (uint*)w;
    ushort* bufA  = (ushort*)w; w += (u_bytes > p_bytes ? u_bytes : p_bytes);
    ushort* bufX  = (ushort*)w;

    const int BLK = 256;
    const int gN = (n_elems + BLK - 1) / BLK;

    // 0) edge dtype detection
    lgcn_detect_kernel<<<1, 128, 0, stream>>>(edge_index, flag);

    // 1) bucket histogram -> scan -> block-aggregated scatter -> bucket CSR
    hipMemsetAsync(bcount, 0, (size_t)NB * sizeof(int), stream);
    hipMemsetAsync(bcur, 0, (size_t)NB * sizeof(int), stream);
    lgcn_bhist_kernel<<<(n_edges + 4095) / 4096, 256, 0, stream>>>(
        edge_index, flag, bcount, n_edges, n_nodes, NB);
    lgcn_bscan_kernel<<<1, 256, 0, stream>>>(bcount, bucketBase, offsets, NB, n_nodes);
    lgcn_bscatter2_kernel<<<(n_edges + CH - 1) / CH, 256, 0, stream>>>(
        edge_index, flag, bucketBase, bcur, pairs, n_edges, n_nodes, NB);
    lgcn_bcsr_kernel<<<NB, 256, 0, stream>>>(
        pairs, bucketBase, offsets, csr_rows, dis, n_nodes);

    // 2) init: out = x (fp32), X = bf16(x)
    lgcn_init_kernel<<<gN, BLK, 0, stream>>>(user_w, item_w, out, bufX,
                                             n_users * EMB, n_elems);

    // 3) 3 pull layers (X -> A -> X -> out), one wave per node
    {
        long long n_thr = (long long)n_nodes * 64;
        int gW = (int)((n_thr + BLK - 1) / BLK);
        lgcn_gather_kernel<false><<<gW, BLK, 0, stream>>>(
            csr_rows, offsets, dis, bufX, bufA, out, n_nodes);
        lgcn_gather_kernel<false><<<gW, BLK, 0, stream>>>(
            csr_rows, offsets, dis, bufA, bufX, out, n_nodes);
        lgcn_gather_kernel<true><<<gW, BLK, 0, stream>>>(
            csr_rows, offsets, dis, bufX, nullptr, out, n_nodes);
    }
}